// Round 2
// baseline (1986.685 us; speedup 1.0000x reference)
//
#include <hip/hip_runtime.h>
#include <hip/hip_bf16.h>
#include <stdint.h>

#define D_ 1024
#define H_ 16
#define F_ 4096
#define S_ 2048
#define V_ 32000

typedef __attribute__((ext_vector_type(8))) short bf16x8;
typedef __attribute__((ext_vector_type(4))) float f32x4;

__device__ __forceinline__ unsigned short f2bf(float f){
  unsigned u = __builtin_bit_cast(unsigned, f);
  u += 0x7fffu + ((u >> 16) & 1u);
  return (unsigned short)(u >> 16);
}
__device__ __forceinline__ float bf2f(unsigned short h){
  unsigned u = ((unsigned)h) << 16;
  return __builtin_bit_cast(float, u);
}

__device__ __forceinline__ void load_lds16(const void* g, void* l){
  __builtin_amdgcn_global_load_lds(
      (__attribute__((address_space(1))) void*)((void*)g),
      (__attribute__((address_space(3))) void*)l, 16, 0, 0);
}

// ---------------------------------------------------------------------------
// GEMM core: C[128x128] = A[M,K](bf16, row-major) x Bt[N,K](bf16, row-major)^T
// 256 threads = 4 waves (2x2), each wave 64x64 = 4x4 mfma_16x16x32 frags.
// LDS tiles [128][64] bf16 with XOR-((row&7)<<4) swizzle applied via
// pre-swizzled global source (global_load_lds writes linearly).
// ---------------------------------------------------------------------------
__device__ __forceinline__ void gemm_core(const unsigned short* __restrict__ A,
                                          const unsigned short* __restrict__ Bt,
                                          int K, int m0, int n0,
                                          f32x4 acc[4][4], char* ldsA, char* ldsB)
{
  const int lane = threadIdx.x & 63;
  const int w    = threadIdx.x >> 6;
  const int wr = (w >> 1) * 64, wc = (w & 1) * 64;
  const int srow = lane >> 3;                  // row within 8-row stripe
  const int scol = ((lane & 7) ^ srow) << 3;   // pre-swizzled element offset
  const int lrow = lane & 15;
  const int lgrp = lane >> 4;

  #pragma unroll
  for (int mi = 0; mi < 4; ++mi)
    #pragma unroll
    for (int ni = 0; ni < 4; ++ni)
      acc[mi][ni] = f32x4{0.f, 0.f, 0.f, 0.f};

  for (int k0 = 0; k0 < K; k0 += 64) {
    __syncthreads();
    #pragma unroll
    for (int i = 0; i < 4; ++i) {
      const int s = w * 4 + i;              // stripe 0..15 (8 rows each)
      const int row = s * 8 + srow;
      load_lds16(A  + (size_t)(m0 + row) * K + k0 + scol, ldsA + s * 1024);
      load_lds16(Bt + (size_t)(n0 + row) * K + k0 + scol, ldsB + s * 1024);
    }
    __syncthreads();
    #pragma unroll
    for (int ks = 0; ks < 2; ++ks) {
      bf16x8 av[4], bv[4];
      #pragma unroll
      for (int mi = 0; mi < 4; ++mi) {
        const int row = wr + mi * 16 + lrow;
        const int g = (ks * 4 + lgrp) ^ (row & 7);
        av[mi] = *(const bf16x8*)(ldsA + row * 128 + g * 16);
      }
      #pragma unroll
      for (int ni = 0; ni < 4; ++ni) {
        const int row = wc + ni * 16 + lrow;
        const int g = (ks * 4 + lgrp) ^ (row & 7);
        bv[ni] = *(const bf16x8*)(ldsB + row * 128 + g * 16);
      }
      #pragma unroll
      for (int mi = 0; mi < 4; ++mi)
        #pragma unroll
        for (int ni = 0; ni < 4; ++ni)
          acc[mi][ni] = __builtin_amdgcn_mfma_f32_16x16x32_bf16(av[mi], bv[ni], acc[mi][ni], 0, 0, 0);
    }
  }
}

__device__ __forceinline__ void epi_bf16(f32x4 acc[4][4], unsigned short* __restrict__ out,
                                         int N, int m0, int n0, float scale)
{
  const int lane = threadIdx.x & 63;
  const int w = threadIdx.x >> 6;
  const int wr = (w >> 1) * 64, wc = (w & 1) * 64;
  const int cr = (lane >> 4) * 4, cc = lane & 15;
  #pragma unroll
  for (int mi = 0; mi < 4; ++mi)
    #pragma unroll
    for (int ni = 0; ni < 4; ++ni)
      #pragma unroll
      for (int r = 0; r < 4; ++r) {
        const int row = m0 + wr + mi * 16 + cr + r;
        const int col = n0 + wc + ni * 16 + cc;
        out[(size_t)row * N + col] = f2bf(acc[mi][ni][r] * scale);
      }
}

__global__ __launch_bounds__(256) void k_gemm_qkv(const unsigned short* __restrict__ A,
    const unsigned short* __restrict__ bq, const unsigned short* __restrict__ bk,
    const unsigned short* __restrict__ bv2, unsigned short* __restrict__ oq,
    unsigned short* __restrict__ ok, unsigned short* __restrict__ ov)
{
  __shared__ __align__(128) char lds[32768];
  const int which = blockIdx.y >> 3;
  const int n0 = (blockIdx.y & 7) * 128, m0 = blockIdx.x * 128;
  const unsigned short* Bt = which == 0 ? bq : (which == 1 ? bk : bv2);
  unsigned short* out = which == 0 ? oq : (which == 1 ? ok : ov);
  const float scale = which == 0 ? 0.125f : 1.f;   // fold HD^-0.5 into Q
  f32x4 acc[4][4];
  gemm_core(A, Bt, 1024, m0, n0, acc, lds, lds + 16384);
  epi_bf16(acc, out, 1024, m0, n0, scale);
}

__global__ __launch_bounds__(256) void k_gemm_w13(const unsigned short* __restrict__ A,
    const unsigned short* __restrict__ b1, const unsigned short* __restrict__ b3,
    unsigned short* __restrict__ o1, unsigned short* __restrict__ o3)
{
  __shared__ __align__(128) char lds[32768];
  const int which = blockIdx.y >> 5;
  const int n0 = (blockIdx.y & 31) * 128, m0 = blockIdx.x * 128;
  const unsigned short* Bt = which == 0 ? b1 : b3;
  unsigned short* out = which == 0 ? o1 : o3;
  f32x4 acc[4][4];
  gemm_core(A, Bt, 1024, m0, n0, acc, lds, lds + 16384);
  epi_bf16(acc, out, 4096, m0, n0, 1.f);
}

__global__ __launch_bounds__(256) void k_gemm_res(const unsigned short* __restrict__ A,
    const unsigned short* __restrict__ Bt, float* __restrict__ x, int K)
{
  __shared__ __align__(128) char lds[32768];
  const int m0 = blockIdx.x * 128, n0 = blockIdx.y * 128;
  f32x4 acc[4][4];
  gemm_core(A, Bt, K, m0, n0, acc, lds, lds + 16384);
  const int lane = threadIdx.x & 63, w = threadIdx.x >> 6;
  const int wr = (w >> 1) * 64, wc = (w & 1) * 64, cr = (lane >> 4) * 4, cc = lane & 15;
  #pragma unroll
  for (int mi = 0; mi < 4; ++mi)
    #pragma unroll
    for (int ni = 0; ni < 4; ++ni)
      #pragma unroll
      for (int r = 0; r < 4; ++r) {
        const size_t idx = (size_t)(m0 + wr + mi * 16 + cr + r) * 1024 + n0 + wc + ni * 16 + cc;
        x[idx] += acc[mi][ni][r];
      }
}

__global__ __launch_bounds__(256) void k_gemm_f32(const unsigned short* __restrict__ A,
    const unsigned short* __restrict__ Bt, float* __restrict__ out, int K, int N)
{
  __shared__ __align__(128) char lds[32768];
  const int m0 = blockIdx.x * 128, n0 = blockIdx.y * 128;
  f32x4 acc[4][4];
  gemm_core(A, Bt, K, m0, n0, acc, lds, lds + 16384);
  const int lane = threadIdx.x & 63, w = threadIdx.x >> 6;
  const int wr = (w >> 1) * 64, wc = (w & 1) * 64, cr = (lane >> 4) * 4, cc = lane & 15;
  #pragma unroll
  for (int mi = 0; mi < 4; ++mi)
    #pragma unroll
    for (int ni = 0; ni < 4; ++ni)
      #pragma unroll
      for (int r = 0; r < 4; ++r)
        out[(size_t)(m0 + wr + mi * 16 + cr + r) * N + n0 + wc + ni * 16 + cc] = acc[mi][ni][r];
}

// ---------------------------------------------------------------------------
// Flash attention: one block per (q-tile of 64 rows, head). 4 waves x 16 rows.
// K tile [64kv][64hd] and Vt tile [64hd][64kv] in swizzled LDS; P via LDS.
// q is pre-scaled by 0.125 in the QKV epilogue.
// ---------------------------------------------------------------------------
__global__ __launch_bounds__(256) void k_attn(const unsigned short* __restrict__ qg,
    const unsigned short* __restrict__ kg, const unsigned short* __restrict__ vtg,
    unsigned short* __restrict__ og)
{
  __shared__ __align__(128) char lk[8192];
  __shared__ __align__(128) char lv[8192];
  __shared__ __align__(128) char lp[8192];
  const int qt = blockIdx.x, head = blockIdx.y;
  const int lane = threadIdx.x & 63, w = threadIdx.x >> 6;
  const int lrow = lane & 15, lgrp = lane >> 4;
  const int srow = lane >> 3;
  const int scol = ((lane & 7) ^ srow) << 3;

  bf16x8 aq[2];
  {
    const int qrow = qt * 64 + w * 16 + lrow;
    #pragma unroll
    for (int s = 0; s < 2; ++s)
      aq[s] = *(const bf16x8*)(qg + (size_t)qrow * D_ + head * 64 + s * 32 + lgrp * 8);
  }
  f32x4 oacc[4];
  #pragma unroll
  for (int i = 0; i < 4; ++i) oacc[i] = f32x4{0.f, 0.f, 0.f, 0.f};
  float mrun[4], lrun[4];
  #pragma unroll
  for (int r = 0; r < 4; ++r) { mrun[r] = -INFINITY; lrun[r] = 0.f; }

  for (int kt = 0; kt <= qt; ++kt) {
    const int kv0 = kt * 64;
    __syncthreads();
    #pragma unroll
    for (int i = 0; i < 2; ++i) {
      const int s = w * 2 + i;
      const int row = s * 8 + srow;
      load_lds16(kg  + (size_t)(kv0 + row) * D_ + head * 64 + scol, lk + s * 1024);
      load_lds16(vtg + (size_t)(head * 64 + row) * S_ + kv0 + scol, lv + s * 1024);
    }
    __syncthreads();

    f32x4 sc[4];
    #pragma unroll
    for (int i = 0; i < 4; ++i) sc[i] = f32x4{0.f, 0.f, 0.f, 0.f};
    #pragma unroll
    for (int ks = 0; ks < 2; ++ks)
      #pragma unroll
      for (int nf = 0; nf < 4; ++nf) {
        const int row = nf * 16 + lrow;
        const int g = (ks * 4 + lgrp) ^ (row & 7);
        bf16x8 bk = *(const bf16x8*)(lk + row * 128 + g * 16);
        sc[nf] = __builtin_amdgcn_mfma_f32_16x16x32_bf16(aq[ks], bk, sc[nf], 0, 0, 0);
      }

    if (kt == qt) {  // causal mask on the diagonal tile
      const int qbase = qt * 64 + w * 16 + lgrp * 4;
      #pragma unroll
      for (int nf = 0; nf < 4; ++nf) {
        const int kvg = kv0 + nf * 16 + lrow;
        #pragma unroll
        for (int r = 0; r < 4; ++r)
          if (kvg > qbase + r) sc[nf][r] = -1e30f;
      }
    }

    float fsc[4], mnew[4];
    #pragma unroll
    for (int r = 0; r < 4; ++r) {
      float mx = fmaxf(fmaxf(sc[0][r], sc[1][r]), fmaxf(sc[2][r], sc[3][r]));
      #pragma unroll
      for (int off = 1; off < 16; off <<= 1) mx = fmaxf(mx, __shfl_xor(mx, off));
      mnew[r] = fmaxf(mrun[r], mx);
      fsc[r] = __expf(mrun[r] - mnew[r]);
      mrun[r] = mnew[r];
    }
    float rsum[4] = {0.f, 0.f, 0.f, 0.f};
    #pragma unroll
    for (int nf = 0; nf < 4; ++nf)
      #pragma unroll
      for (int r = 0; r < 4; ++r) {
        const float p = __expf(sc[nf][r] - mnew[r]);
        rsum[r] += p;
        const int rowq = lgrp * 4 + r;
        *(unsigned short*)(lp + w * 2048 + rowq * 128 +
                           (((nf * 16 + lrow) * 2) ^ ((rowq & 7) << 4))) = f2bf(p);
      }
    #pragma unroll
    for (int r = 0; r < 4; ++r) {
      #pragma unroll
      for (int off = 1; off < 16; off <<= 1) rsum[r] += __shfl_xor(rsum[r], off);
      lrun[r] = lrun[r] * fsc[r] + rsum[r];
    }
    #pragma unroll
    for (int hf = 0; hf < 4; ++hf)
      #pragma unroll
      for (int r = 0; r < 4; ++r) oacc[hf][r] *= fsc[r];

    #pragma unroll
    for (int ks = 0; ks < 2; ++ks) {
      const int g0 = (ks * 4 + lgrp) ^ (lrow & 7);
      bf16x8 ap = *(const bf16x8*)(lp + w * 2048 + lrow * 128 + g0 * 16);
      #pragma unroll
      for (int hf = 0; hf < 4; ++hf) {
        const int row = hf * 16 + lrow;
        const int g = (ks * 4 + lgrp) ^ (row & 7);
        bf16x8 bvv = *(const bf16x8*)(lv + row * 128 + g * 16);
        oacc[hf] = __builtin_amdgcn_mfma_f32_16x16x32_bf16(ap, bvv, oacc[hf], 0, 0, 0);
      }
    }
  }

  const int qbase = qt * 64 + w * 16 + lgrp * 4;
  #pragma unroll
  for (int hf = 0; hf < 4; ++hf)
    #pragma unroll
    for (int r = 0; r < 4; ++r) {
      const float o = oacc[hf][r] / lrun[r];
      og[(size_t)(qbase + r) * D_ + head * 64 + hf * 16 + lrow] = f2bf(o);
    }
}

// ---------------------------------------------------------------------------
// Small kernels
// ---------------------------------------------------------------------------
__global__ void k_embed(const int* __restrict__ ids, const float* __restrict__ emb,
                        const float* __restrict__ pos, float* __restrict__ x)
{
  const int s = blockIdx.x;
  const int d = threadIdx.x * 4;
  const int id = ids[s];
  const float4 e = *(const float4*)(emb + (size_t)id * D_ + d);
  const float4 p = *(const float4*)(pos + (size_t)s * D_ + d);
  float4 o; o.x = e.x + p.x; o.y = e.y + p.y; o.z = e.z + p.z; o.w = e.w + p.w;
  *(float4*)(x + (size_t)s * D_ + d) = o;
}

__global__ void k_rmsnorm(const float* __restrict__ x, const float* __restrict__ g,
                          unsigned short* __restrict__ h)
{
  __shared__ float red[4];
  const int row = blockIdx.x, t = threadIdx.x;
  const float4 v = *(const float4*)(x + (size_t)row * D_ + t * 4);
  float ss = v.x * v.x + v.y * v.y + v.z * v.z + v.w * v.w;
  #pragma unroll
  for (int off = 32; off > 0; off >>= 1) ss += __shfl_xor(ss, off);
  if ((t & 63) == 0) red[t >> 6] = ss;
  __syncthreads();
  const float tot = red[0] + red[1] + red[2] + red[3];
  const float rs = rsqrtf(tot * (1.f / 1024.f) + 1e-6f);
  const float4 gg = *(const float4*)(g + t * 4);
  ushort4 o;
  o.x = f2bf(v.x * rs * gg.x); o.y = f2bf(v.y * rs * gg.y);
  o.z = f2bf(v.z * rs * gg.z); o.w = f2bf(v.w * rs * gg.w);
  *(ushort4*)(h + (size_t)row * D_ + t * 4) = o;
}

__global__ void k_silu(unsigned short* __restrict__ fa, const unsigned short* __restrict__ fb)
{
  const size_t i = (size_t)blockIdx.x * blockDim.x + threadIdx.x;  // per 8 elems
  uint4 va = ((const uint4*)fa)[i];
  uint4 vb = ((const uint4*)fb)[i];
  unsigned short* pa = (unsigned short*)&va;
  const unsigned short* pb = (const unsigned short*)&vb;
  unsigned short ro[8];
  #pragma unroll
  for (int j = 0; j < 8; ++j) {
    const float a = bf2f(pa[j]), b = bf2f(pb[j]);
    const float s = a / (1.f + __expf(-a));
    ro[j] = f2bf(s * b);
  }
  ((uint4*)fa)[i] = *(uint4*)ro;
}

// fp32 [K][N] -> bf16 [N][K]
__global__ void k_transpose_f2b(const float* __restrict__ in, unsigned short* __restrict__ outp,
                                int K, int N)
{
  __shared__ float t[32][33];
  const int nb = blockIdx.x * 32, kb = blockIdx.y * 32;
  const float* src = in + (size_t)blockIdx.z * K * N;
  unsigned short* dst = outp + (size_t)blockIdx.z * K * N;
  const int tx = threadIdx.x, ty = threadIdx.y;
  #pragma unroll
  for (int i = 0; i < 4; ++i)
    t[ty + i * 8][tx] = src[(size_t)(kb + ty + i * 8) * N + nb + tx];
  __syncthreads();
  #pragma unroll
  for (int i = 0; i < 4; ++i)
    dst[(size_t)(nb + ty + i * 8) * K + kb + tx] = f2bf(t[tx][ty + i * 8]);
}

// bf16 [R][C] -> bf16 [C][R]
__global__ void k_transpose_b(const unsigned short* __restrict__ in,
                              unsigned short* __restrict__ outp, int R, int C)
{
  __shared__ unsigned short t[32][33];
  const int cb = blockIdx.x * 32, rb = blockIdx.y * 32;
  const int tx = threadIdx.x, ty = threadIdx.y;
  #pragma unroll
  for (int i = 0; i < 4; ++i)
    t[ty + i * 8][tx] = in[(size_t)(rb + ty + i * 8) * C + cb + tx];
  __syncthreads();
  #pragma unroll
  for (int i = 0; i < 4; ++i)
    outp[(size_t)(cb + ty + i * 8) * R + rb + tx] = t[tx][ty + i * 8];
}

// ---------------------------------------------------------------------------
extern "C" void kernel_launch(void* const* d_in, const int* in_sizes, int n_in,
                              void* d_out, int out_size, void* d_ws, size_t ws_size,
                              hipStream_t stream)
{
  const int*   ids  = (const int*)d_in[0];
  const float* emb  = (const float*)d_in[1];
  const float* pos  = (const float*)d_in[2];
  const float* ga   = (const float*)d_in[3];
  const float* wq   = (const float*)d_in[4];
  const float* wk   = (const float*)d_in[5];
  const float* wv   = (const float*)d_in[6];
  const float* wo   = (const float*)d_in[7];
  const float* gf   = (const float*)d_in[8];
  const float* w1   = (const float*)d_in[9];
  const float* w2   = (const float*)d_in[10];
  const float* w3   = (const float*)d_in[11];
  const float* gfin = (const float*)d_in[12];
  const float* wlm  = (const float*)d_in[13];
  float* out = (float*)d_out;
  (void)in_sizes; (void)n_in; (void)out_size; (void)ws_size;

  char* ws = (char*)d_ws;
  size_t off = 0;
  auto take = [&](size_t b) -> char* {
    char* p = ws + off; off += (b + 1023) & ~(size_t)1023; return p;
  };
  const size_t DD = (size_t)1024 * 1024, DF = (size_t)1024 * 4096;
  unsigned short* wqt  = (unsigned short*)take(4 * DD * 2);
  unsigned short* wkt  = (unsigned short*)take(4 * DD * 2);
  unsigned short* wvt  = (unsigned short*)take(4 * DD * 2);
  unsigned short* wot  = (unsigned short*)take(4 * DD * 2);
  unsigned short* w1t  = (unsigned short*)take(4 * DF * 2);
  unsigned short* w3t  = (unsigned short*)take(4 * DF * 2);
  unsigned short* w2t  = (unsigned short*)take(4 * DF * 2);
  unsigned short* wlmt = (unsigned short*)take((size_t)V_ * 1024 * 2);
  float*          x    = (float*)take((size_t)2048 * 1024 * 4);
  unsigned short* hb   = (unsigned short*)take((size_t)2048 * 1024 * 2);
  unsigned short* qb   = (unsigned short*)take((size_t)2048 * 1024 * 2);
  unsigned short* kb   = (unsigned short*)take((size_t)2048 * 1024 * 2);
  unsigned short* vb   = (unsigned short*)take((size_t)2048 * 1024 * 2);
  unsigned short* vtb  = (unsigned short*)take((size_t)2048 * 1024 * 2);
  unsigned short* ab   = (unsigned short*)take((size_t)2048 * 1024 * 2);
  unsigned short* fa   = (unsigned short*)take((size_t)2048 * 4096 * 2);
  unsigned short* fb   = (unsigned short*)take((size_t)2048 * 4096 * 2);

  const dim3 tb(32, 8);
  k_transpose_f2b<<<dim3(32, 32, 4),   tb, 0, stream>>>(wq,  wqt,  1024, 1024);
  k_transpose_f2b<<<dim3(32, 32, 4),   tb, 0, stream>>>(wk,  wkt,  1024, 1024);
  k_transpose_f2b<<<dim3(32, 32, 4),   tb, 0, stream>>>(wv,  wvt,  1024, 1024);
  k_transpose_f2b<<<dim3(32, 32, 4),   tb, 0, stream>>>(wo,  wot,  1024, 1024);
  k_transpose_f2b<<<dim3(128, 32, 4),  tb, 0, stream>>>(w1,  w1t,  1024, 4096);
  k_transpose_f2b<<<dim3(128, 32, 4),  tb, 0, stream>>>(w3,  w3t,  1024, 4096);
  k_transpose_f2b<<<dim3(32, 128, 4),  tb, 0, stream>>>(w2,  w2t,  4096, 1024);
  k_transpose_f2b<<<dim3(1000, 32, 1), tb, 0, stream>>>(wlm, wlmt, 1024, V_);

  k_embed<<<2048, 256, 0, stream>>>(ids, emb, pos, x);

  for (int i = 0; i < 4; ++i) {
    k_rmsnorm<<<2048, 256, 0, stream>>>(x, ga + i * 1024, hb);
    k_gemm_qkv<<<dim3(16, 24), 256, 0, stream>>>(hb, wqt + i * DD, wkt + i * DD, wvt + i * DD,
                                                 qb, kb, vb);
    k_transpose_b<<<dim3(32, 64), tb, 0, stream>>>(vb, vtb, 2048, 1024);
    k_attn<<<dim3(32, 16), 256, 0, stream>>>(qb, kb, vtb, ab);
    k_gemm_res<<<dim3(16, 8), 256, 0, stream>>>(ab, wot + i * DD, x, 1024);
    k_rmsnorm<<<2048, 256, 0, stream>>>(x, gf + i * 1024, hb);
    k_gemm_w13<<<dim3(16, 64), 256, 0, stream>>>(hb, w1t + i * DF, w3t + i * DF, fa, fb);
    k_silu<<<4096, 256, 0, stream>>>(fa, fb);
    k_gemm_res<<<dim3(16, 8), 256, 0, stream>>>(fa, w2t + i * DF, x, 4096);
  }
  k_rmsnorm<<<2048, 256, 0, stream>>>(x, gfin, hb);
  k_gemm_f32<<<dim3(16, 250), 256, 0, stream>>>(hb, wlmt, out, 1024, V_);
}